// Round 7
// baseline (84.347 us; speedup 1.0000x reference)
//
#include <hip/hip_runtime.h>
#include <math.h>

#define NPTS    32
#define UNITS   64
#define PTOT    40000
#define NPAIRS  (PTOT / 2)          // 20000
#define SBLOCKS 2500
#define WPB     4                   // waves per block (256 threads)
#define TOTW    (SBLOCKS * WPB)     // 10000 waves
#define PPW     (NPAIRS / TOTW)     // 2 pairs per wave (exact)

// x[p,n,u] = b[p,u] + f0*wp0 + f1*wp1 + f2*wp2 + f3*wp3  (per lane = unit)
// wp folds W rows: wp0=W0+W4+W7, wp1=W1+W5+W8, wp2=W2+W6, wp3=W3
// b = -(m0*W4 + m1*W5 + m2*W6 + cx*W7 + cy*W8)
// sg = sign(gamma[u]) folded into weights: chain yields x' = sg*x, track max(x').
// Point data enters via WAVE-UNIFORM addresses -> s_load -> SGPR operands of
// the FMAs (scalar-mem pipe runs parallel to VALU; no LDS, no readlane hazard).
// Inner loop: static chunks of 8 points, fully unrolled, wave-uniform
// predication; uniform break between chunks.

__global__ __launch_bounds__(256)
void pfn_main(const float* __restrict__ feat,
              const int*   __restrict__ nvox,
              const int*   __restrict__ coors,
              const float* __restrict__ Wm,
              const float* __restrict__ gamma,
              float*       __restrict__ xext,
              float*       __restrict__ accum)
{
    __shared__ float ps[WPB][128];

    const int tid  = threadIdx.x;
    const int lane = tid & 63;
    const int wave = __builtin_amdgcn_readfirstlane(tid >> 6);
    const int gwave = blockIdx.x * WPB + wave;

    const float sg  = (gamma[lane] >= 0.f) ? 1.f : -1.f;
    const float w4 = sg * Wm[4 * UNITS + lane], w5 = sg * Wm[5 * UNITS + lane];
    const float w6 = sg * Wm[6 * UNITS + lane], w7 = sg * Wm[7 * UNITS + lane];
    const float w8 = sg * Wm[8 * UNITS + lane];
    const float wp0 = sg * Wm[0 * UNITS + lane] + w4 + w7;
    const float wp1 = sg * Wm[1 * UNITS + lane] + w5 + w8;
    const float wp2 = sg * Wm[2 * UNITS + lane] + w6;
    const float wp3 = sg * Wm[3 * UNITS + lane];

    float lsum = 0.f, lsq = 0.f;   // sums of x' = sg*x

    #pragma unroll
    for (int it = 0; it < PPW; ++it) {
        const int pair = it * TOTW + gwave;   // uniform
        const int p0 = pair * 2;              // uniform

        // coalesced vector load (1 KB/wave) only for the points-mean butterfly
        const float4 f4 = *reinterpret_cast<const float4*>(feat + (size_t)pair * 256 + lane * 4);
        float sx = f4.x, sy = f4.y, sz = f4.z;
        #pragma unroll
        for (int off = 1; off < 32; off <<= 1) {
            sx += __shfl_xor(sx, off);
            sy += __shfl_xor(sy, off);
            sz += __shfl_xor(sz, off);
        }

        int nvA = nvox[p0], nvB = nvox[p0 + 1];       // uniform -> s_load
        nvA = nvA < 1 ? 1 : (nvA > NPTS ? NPTS : nvA);
        nvB = nvB < 1 ? 1 : (nvB > NPTS ? NPTS : nvB);
        const float cxA = (float)coors[p0 * 4 + 3] * 0.2f + 0.1f;
        const float cyA = (float)coors[p0 * 4 + 2] * 0.2f + (-39.9f);
        const float cxB = (float)coors[p0 * 4 + 7] * 0.2f + 0.1f;
        const float cyB = (float)coors[p0 * 4 + 6] * 0.2f + (-39.9f);
        const float iA  = 1.f / (float)nvA,  iB  = 1.f / (float)nvB;
        const float mA0 = __shfl(sx, 0)  * iA, mA1 = __shfl(sy, 0)  * iA, mA2 = __shfl(sz, 0)  * iA;
        const float mB0 = __shfl(sx, 32) * iB, mB1 = __shfl(sy, 32) * iB, mB2 = __shfl(sz, 32) * iB;
        const float bA = -(mA0 * w4 + mA1 * w5 + mA2 * w6 + cxA * w7 + cyA * w8);
        const float bB = -(mB0 * w4 + mB1 * w5 + mB2 * w6 + cxB * w7 + cyB * w8);

        // uniform point bases: whole wave reads the same point -> s_load
        const float* fpA = feat + (size_t)p0 * 128;
        const float* fpB = fpA + 128;

        float mA = -3.4e38f, mB = -3.4e38f;
        const int nmax = nvA > nvB ? nvA : nvB;       // uniform

        #pragma unroll 1
        for (int c = 0; c < NPTS; c += 8) {
            if (c >= nmax) break;                     // uniform scalar branch
            #pragma unroll
            for (int k = 0; k < 8; ++k) {
                const int n = c + k;
                const float4 a  = *reinterpret_cast<const float4*>(fpA + n * 4);
                const float4 b4 = *reinterpret_cast<const float4*>(fpB + n * 4);
                const float xA = fmaf(a.x,  wp0, fmaf(a.y,  wp1, fmaf(a.z,  wp2, fmaf(a.w,  wp3, bA))));
                const float xB = fmaf(b4.x, wp0, fmaf(b4.y, wp1, fmaf(b4.z, wp2, fmaf(b4.w, wp3, bB))));
                const float gA = (n < nvA) ? 1.f : 0.f;     // uniform masks
                const float gB = (n < nvB) ? 1.f : 0.f;
                const float xAm = xA * gA, xBm = xB * gB;
                lsum += xAm;  lsq = fmaf(xAm, xA, lsq);
                lsum += xBm;  lsq = fmaf(xBm, xB, lsq);
                mA = fmaxf(mA, (n < nvA) ? xA : -3.4e38f);
                mB = fmaxf(mB, (n < nvB) ? xB : -3.4e38f);
            }
        }

        xext[(size_t)p0 * UNITS + lane]       = sg * mA;
        xext[(size_t)(p0 + 1) * UNITS + lane] = sg * mB;
    }

    ps[wave][lane]      = sg * lsum;   // Σx = sg * Σx'
    ps[wave][64 + lane] = lsq;         // x'^2 == x^2
    __syncthreads();
    if (tid < 128) {
        const float v = ps[0][tid] + ps[1][tid] + ps[2][tid] + ps[3][tid];
        atomicAdd(&accum[tid], v);     // device-scope; 128 addresses, end-of-block
    }
}

// Apply: per-block inline BN finalize from the 128-float accumulator, then
// streaming out[p,u] = max(scale*ext+shift, [nv<32 ? max(shift,0) : 0]).
#define CBLOCKS 2500   // 2500*256 threads * 1 float4 = 2,560,000 floats exactly

__global__ __launch_bounds__(256)
void pfn_apply(const float*  __restrict__ accum,
               const float*  __restrict__ gamma,
               const float*  __restrict__ beta,
               const float4* __restrict__ xext,
               const int*    __restrict__ nvox,
               float4*       __restrict__ out)
{
    __shared__ __align__(16) float s_sc[64], s_sh[64];
    const int t = threadIdx.x;
    if (t < 64) {
        const float INV_PN = 1.0f / (float)(PTOT * NPTS);
        const float S = accum[t], Q = accum[64 + t];
        const float mean  = S * INV_PN;
        const float var   = Q * INV_PN - mean * mean;
        const float scale = gamma[t] * rsqrtf(var + 1e-3f);
        s_sc[t] = scale;
        s_sh[t] = beta[t] - mean * scale;
    }
    __syncthreads();

    const int i  = blockIdx.x * 256 + t;     // float4 index
    const int u0 = (i & 15) * 4;             // first unit of this quad
    const int p  = i >> 4;                   // pillar
    const float4 sc = *reinterpret_cast<const float4*>(&s_sc[u0]);
    const float4 sh = *reinterpret_cast<const float4*>(&s_sh[u0]);
    const float4 e  = xext[i];
    const bool pad  = nvox[p] < NPTS;
    float4 o;
    o.x = fmaxf(fmaf(e.x, sc.x, sh.x), pad ? fmaxf(sh.x, 0.f) : 0.f);
    o.y = fmaxf(fmaf(e.y, sc.y, sh.y), pad ? fmaxf(sh.y, 0.f) : 0.f);
    o.z = fmaxf(fmaf(e.z, sc.z, sh.z), pad ? fmaxf(sh.z, 0.f) : 0.f);
    o.w = fmaxf(fmaf(e.w, sc.w, sh.w), pad ? fmaxf(sh.w, 0.f) : 0.f);
    out[i] = o;
}

extern "C" void kernel_launch(void* const* d_in, const int* in_sizes, int n_in,
                              void* d_out, int out_size, void* d_ws, size_t ws_size,
                              hipStream_t stream)
{
    const float* feat  = (const float*)d_in[0];
    const int*   nvox  = (const int*)d_in[1];
    const int*   coors = (const int*)d_in[2];
    const float* Wm    = (const float*)d_in[3];
    const float* gamma = (const float*)d_in[4];
    const float* beta  = (const float*)d_in[5];
    float* out = (float*)d_out;

    float* xext  = (float*)d_ws;                       // P*U floats = 10.24 MB
    float* accum = xext + (size_t)PTOT * UNITS;        // 128 floats (sum, sumsq)

    hipMemsetAsync(accum, 0, 128 * sizeof(float), stream);   // ws is poisoned, not re-zeroed
    pfn_main<<<SBLOCKS, 256, 0, stream>>>(feat, nvox, coors, Wm, gamma, xext, accum);
    pfn_apply<<<CBLOCKS, 256, 0, stream>>>(accum, gamma, beta,
                                           (const float4*)xext, nvox, (float4*)out);
}

// Round 8
// 47.758 us; speedup vs baseline: 1.7661x; 1.7661x over previous
//
#include <hip/hip_runtime.h>
#include <math.h>

#define NPTS    32
#define UNITS   64
#define PTOT    40000
#define NPAIRS  (PTOT / 2)          // 20000
#define SBLOCKS 2500
#define WPB     4                   // waves per block (256 threads)
#define TOTW    (SBLOCKS * WPB)     // 10000 waves
#define PPW     (NPAIRS / TOTW)     // 2 pairs per wave (exact)

// x[p,n,u] = b[p,u] + f0*wp0 + f1*wp1 + f2*wp2 + f3*wp3  (per lane = unit)
// wp folds W rows: wp0=W0+W4+W7, wp1=W1+W5+W8, wp2=W2+W6, wp3=W3
// b = -(m0*W4 + m1*W5 + m2*W6 + cx*W7 + cy*W8)
// sg = sign(gamma[u]) folded: chain yields x' = sg*x, track max(x').
// Point broadcast: LDS uniform-address ds_read_b128 (HW broadcast, in-order
// returns -> partial lgkmcnt waits) + explicit 2-stage register double-buffer.
// NO atomics (R6/R7: 320K RMWs on 128 addrs cost ~60us). Per-block partials.

__global__ __launch_bounds__(256)
void pfn_main(const float* __restrict__ feat,
              const int*   __restrict__ nvox,
              const int*   __restrict__ coors,
              const float* __restrict__ Wm,
              const float* __restrict__ gamma,
              float*       __restrict__ xext,
              float*       __restrict__ partials)
{
    __shared__ float4 sf[WPB][2][NPTS];   // wave-private staging (reused per it)
    __shared__ float  ps[WPB][128];

    const int tid  = threadIdx.x;
    const int lane = tid & 63;
    const int wave = __builtin_amdgcn_readfirstlane(tid >> 6);
    const int gwave = blockIdx.x * WPB + wave;
    const int half = lane >> 5, pt = lane & 31;

    const float sg  = (gamma[lane] >= 0.f) ? 1.f : -1.f;
    const float w4 = sg * Wm[4 * UNITS + lane], w5 = sg * Wm[5 * UNITS + lane];
    const float w6 = sg * Wm[6 * UNITS + lane], w7 = sg * Wm[7 * UNITS + lane];
    const float w8 = sg * Wm[8 * UNITS + lane];
    const float wp0 = sg * Wm[0 * UNITS + lane] + w4 + w7;
    const float wp1 = sg * Wm[1 * UNITS + lane] + w5 + w8;
    const float wp2 = sg * Wm[2 * UNITS + lane] + w6;
    const float wp3 = sg * Wm[3 * UNITS + lane];

    // ---- prefetch: big vector loads + uniform meta (s_load) for both pairs ----
    float4 fv[PPW];
    int nvAv[PPW], nvBv[PPW];
    float cxAv[PPW], cyAv[PPW], cxBv[PPW], cyBv[PPW];
    #pragma unroll
    for (int it = 0; it < PPW; ++it) {
        const int pair = it * TOTW + gwave;     // uniform
        const int p0 = pair * 2;                // uniform
        fv[it] = *reinterpret_cast<const float4*>(feat + (size_t)pair * 256 + lane * 4);
        int nvA = nvox[p0], nvB = nvox[p0 + 1];
        nvAv[it] = nvA < 1 ? 1 : (nvA > NPTS ? NPTS : nvA);
        nvBv[it] = nvB < 1 ? 1 : (nvB > NPTS ? NPTS : nvB);
        cxAv[it] = (float)coors[p0 * 4 + 3] * 0.2f + 0.1f;
        cyAv[it] = (float)coors[p0 * 4 + 2] * 0.2f + (-39.9f);
        cxBv[it] = (float)coors[p0 * 4 + 7] * 0.2f + 0.1f;
        cyBv[it] = (float)coors[p0 * 4 + 6] * 0.2f + (-39.9f);
    }

    float lsumA = 0.f, lsumB = 0.f, lsqA = 0.f, lsqB = 0.f;

    #pragma unroll
    for (int it = 0; it < PPW; ++it) {
        const int pair = it * TOTW + gwave;
        const int p0 = pair * 2;

        // stage this pair's points (same-wave DS ordering makes reuse safe)
        sf[wave][half][pt] = fv[it];

        // per-half xyz sums over all 32 raw points (reference sums unmasked)
        float sx = fv[it].x, sy = fv[it].y, sz = fv[it].z;
        #pragma unroll
        for (int off = 1; off < 32; off <<= 1) {
            sx += __shfl_xor(sx, off);
            sy += __shfl_xor(sy, off);
            sz += __shfl_xor(sz, off);
        }

        const int nvA = nvAv[it], nvB = nvBv[it];
        const float iA = 1.f / (float)nvA, iB = 1.f / (float)nvB;
        const float mA0 = __shfl(sx, 0)  * iA, mA1 = __shfl(sy, 0)  * iA, mA2 = __shfl(sz, 0)  * iA;
        const float mB0 = __shfl(sx, 32) * iB, mB1 = __shfl(sy, 32) * iB, mB2 = __shfl(sz, 32) * iB;
        const float bA = -(mA0 * w4 + mA1 * w5 + mA2 * w6 + cxAv[it] * w7 + cyAv[it] * w8);
        const float bB = -(mB0 * w4 + mB1 * w5 + mB2 * w6 + cxBv[it] * w7 + cyBv[it] * w8);

        float mA = -3.4e38f, mB = -3.4e38f;
        const int nmax = nvA > nvB ? nvA : nvB;   // uniform

        float4 A0[4], B0[4], A1[4], B1[4];        // named dbuf, static indexing only

        auto compute = [&](int cbase, float4 (&A)[4], float4 (&B)[4]) {
            #pragma unroll
            for (int k = 0; k < 4; ++k) {
                const int n = cbase + k;          // uniform
                const float4 a  = A[k];
                const float4 b4 = B[k];
                const float xA = fmaf(a.x,  wp0, fmaf(a.y,  wp1, fmaf(a.z,  wp2, fmaf(a.w,  wp3, bA))));
                const float xB = fmaf(b4.x, wp0, fmaf(b4.y, wp1, fmaf(b4.z, wp2, fmaf(b4.w, wp3, bB))));
                const float xAv = (n < nvA) ? xA : 0.f;   // uniform predicate
                const float xBv = (n < nvB) ? xB : 0.f;
                lsumA += xAv;  lsqA = fmaf(xAv, xA, lsqA);
                lsumB += xBv;  lsqB = fmaf(xBv, xB, lsqB);
                mA = fmaxf(mA, (n < nvA) ? xA : -3.4e38f);
                mB = fmaxf(mB, (n < nvB) ? xB : -3.4e38f);
            }
        };

        // 2-stage software pipeline over chunks of 4 points
        #pragma unroll
        for (int k = 0; k < 4; ++k) { A0[k] = sf[wave][0][k]; B0[k] = sf[wave][1][k]; }
        int c = 0;
        while (true) {
            const bool more = (c + 4 < nmax);     // uniform scalar branch
            if (more) {
                #pragma unroll
                for (int k = 0; k < 4; ++k) { A1[k] = sf[wave][0][c + 4 + k]; B1[k] = sf[wave][1][c + 4 + k]; }
            }
            compute(c, A0, B0);
            if (!more) break;
            c += 4;
            const bool more2 = (c + 4 < nmax);
            if (more2) {
                #pragma unroll
                for (int k = 0; k < 4; ++k) { A0[k] = sf[wave][0][c + 4 + k]; B0[k] = sf[wave][1][c + 4 + k]; }
            }
            compute(c, A1, B1);
            if (!more2) break;
            c += 4;
        }

        xext[(size_t)p0 * UNITS + lane]       = sg * mA;
        xext[(size_t)(p0 + 1) * UNITS + lane] = sg * mB;
    }

    ps[wave][lane]      = sg * (lsumA + lsumB);   // Σx = sg * Σx'
    ps[wave][64 + lane] = lsqA + lsqB;            // x'^2 == x^2
    __syncthreads();
    if (tid < 128)
        partials[blockIdx.x * 128 + tid] = ps[0][tid] + ps[1][tid] + ps[2][tid] + ps[3][tid];
}

__global__ __launch_bounds__(256)
void pfn_finalize(const float* __restrict__ partials,
                  const float* __restrict__ gamma,
                  const float* __restrict__ beta,
                  float*       __restrict__ ss)
{
    const int u = blockIdx.x;   // 0..63
    const int t = threadIdx.x;  // 0..255
    double aS = 0.0, aQ = 0.0;
    for (int b = t; b < SBLOCKS; b += 256) {
        aS += (double)partials[b * 128 + u];
        aQ += (double)partials[b * 128 + 64 + u];
    }
    __shared__ double sS[256], sQ[256];
    sS[t] = aS; sQ[t] = aQ;
    __syncthreads();
    for (int s = 128; s > 0; s >>= 1) {
        if (t < s) { sS[t] += sS[t + s]; sQ[t] += sQ[t + s]; }
        __syncthreads();
    }
    if (t == 0) {
        const double inv_pn = 1.0 / ((double)PTOT * (double)NPTS);
        const double mean = sS[0] * inv_pn;
        const double var  = sQ[0] * inv_pn - mean * mean;
        const float scale = gamma[u] * (float)(1.0 / sqrt(var + 1e-3));
        const float shift = beta[u] - (float)mean * scale;
        ss[u]      = scale;
        ss[64 + u] = shift;
    }
}

// Apply: streaming, one float4 (4 consecutive units) per thread.
#define CBLOCKS 2500   // 2500*256 threads * 1 float4 = 2,560,000 floats exactly

__global__ __launch_bounds__(256)
void pfn_apply(const float*  __restrict__ ss,
               const float4* __restrict__ xext,
               const int*    __restrict__ nvox,
               float4*       __restrict__ out)
{
    const int i  = blockIdx.x * 256 + threadIdx.x;   // float4 index
    const int u0 = (i & 15) * 4;                     // first unit of this quad
    const int p  = i >> 4;                           // pillar
    const float4 sc = *reinterpret_cast<const float4*>(ss + u0);
    const float4 sh = *reinterpret_cast<const float4*>(ss + 64 + u0);
    const float4 e  = xext[i];
    const bool pad  = nvox[p] < NPTS;
    float4 o;
    o.x = fmaxf(fmaf(e.x, sc.x, sh.x), pad ? fmaxf(sh.x, 0.f) : 0.f);
    o.y = fmaxf(fmaf(e.y, sc.y, sh.y), pad ? fmaxf(sh.y, 0.f) : 0.f);
    o.z = fmaxf(fmaf(e.z, sc.z, sh.z), pad ? fmaxf(sh.z, 0.f) : 0.f);
    o.w = fmaxf(fmaf(e.w, sc.w, sh.w), pad ? fmaxf(sh.w, 0.f) : 0.f);
    out[i] = o;
}

extern "C" void kernel_launch(void* const* d_in, const int* in_sizes, int n_in,
                              void* d_out, int out_size, void* d_ws, size_t ws_size,
                              hipStream_t stream)
{
    const float* feat  = (const float*)d_in[0];
    const int*   nvox  = (const int*)d_in[1];
    const int*   coors = (const int*)d_in[2];
    const float* Wm    = (const float*)d_in[3];
    const float* gamma = (const float*)d_in[4];
    const float* beta  = (const float*)d_in[5];
    float* out = (float*)d_out;

    float* xext     = (float*)d_ws;                      // P*U floats = 10.24 MB
    float* partials = xext + (size_t)PTOT * UNITS;       // SBLOCKS*128 floats = 1.28 MB
    float* ss       = partials + (size_t)SBLOCKS * 128;  // 128 floats

    pfn_main<<<SBLOCKS, 256, 0, stream>>>(feat, nvox, coors, Wm, gamma, xext, partials);
    pfn_finalize<<<UNITS, 256, 0, stream>>>(partials, gamma, beta, ss);
    pfn_apply<<<CBLOCKS, 256, 0, stream>>>(ss, (const float4*)xext, nvox, (float4*)out);
}

// Round 9
// 39.716 us; speedup vs baseline: 2.1238x; 1.2025x over previous
//
#include <hip/hip_runtime.h>
#include <hip/hip_bf16.h>
#include <math.h>

#define NPTS    32
#define UNITS   64
#define PTOT    40000
#define NPAIRS  (PTOT / 2)          // 20000
#define SBLOCKS 2500
#define WPB     4                   // waves per block (256 threads)
#define TOTW    (SBLOCKS * WPB)     // 10000 waves
#define PPW     (NPAIRS / TOTW)     // 2 pairs per wave (exact)

// Per pillar: x[n,u] = feats9[n,:] . W9[:,u]  -- a 32x64x9 GEMM done with
// 2x mfma_f32_32x32x16_bf16 (K=16, rows 9..15 zero).
// k-order: [x,y,z,i, x-m0,y-m1,z-m2, x-cx, y-cy].
// sg = sign(gamma[u]) folded into B so max works monotonically: x' = sg*x.
// A rows n>=nv are ZEROED -> padded x' == 0 exactly (matches reference's
// mask-then-matmul), so BN sums need no masking, max includes the 0 rows,
// and apply needs no nvox/padc: out = relu(|scale|*ext' + shift).
// A-frag (inferred layout): lane l holds A[row=l&31][k=8*(l>>5)+i], i=0..7.
// B-frag:                   lane l holds B[k=8*(l>>5)+i][col=l&31].
// C/D (HW-verified m74/m101): col=lane&31, row=(reg&3)+8*(reg>>2)+4*(lane>>5).
// Epilogue only relies on col=lane&31 (row-agnostic sums/max).

typedef __attribute__((ext_vector_type(8)))  short short8v;
typedef __attribute__((ext_vector_type(16))) float f32x16;

__device__ __forceinline__ unsigned short f2bf(float f) {
    __hip_bfloat16 h = __float2bfloat16(f);
    return *reinterpret_cast<unsigned short*>(&h);
}
__device__ __forceinline__ unsigned pk2(float lo, float hi) {
    return ((unsigned)f2bf(hi) << 16) | (unsigned)f2bf(lo);
}

__global__ __launch_bounds__(256)
void pfn_main(const float* __restrict__ feat,
              const int*   __restrict__ nvox,
              const int*   __restrict__ coors,
              const float* __restrict__ Wm,
              const float* __restrict__ gamma,
              float*       __restrict__ xext,
              float*       __restrict__ partials)
{
    __shared__ float ps[WPB][128];

    const int tid  = threadIdx.x;
    const int lane = tid & 63;
    const int wave = __builtin_amdgcn_readfirstlane(tid >> 6);
    const int gwave = blockIdx.x * WPB + wave;
    const int c31  = lane & 31;
    const bool hiL = (lane >= 32);

    // ---- B fragments (sg-folded bf16 weights), built once ----
    short8v Bf[2];
    #pragma unroll
    for (int t = 0; t < 2; ++t) {
        const int colg = 32 * t + c31;
        const float sgc = (gamma[colg] >= 0.f) ? 1.f : -1.f;
        const int k0 = hiL ? 8 : 0;
        float bv[8];
        #pragma unroll
        for (int i = 0; i < 8; ++i) {
            const int k = k0 + i;
            bv[i] = (k < 9) ? sgc * Wm[k * UNITS + colg] : 0.f;
        }
        union { unsigned u[4]; short8v v; } B_;
        B_.u[0] = pk2(bv[0], bv[1]); B_.u[1] = pk2(bv[2], bv[3]);
        B_.u[2] = pk2(bv[4], bv[5]); B_.u[3] = pk2(bv[6], bv[7]);
        Bf[t] = B_.v;
    }

    float lsum = 0.f, lsq = 0.f;   // per-lane: unit `lane` partial sums of x', x'^2

    #pragma unroll
    for (int it = 0; it < PPW; ++it) {
        const int pair = it * TOTW + gwave;   // uniform
        const int p0 = pair * 2;              // uniform

        // coalesced: lanes 0..31 = pillar p0's 32 points, 32..63 = p0+1
        const float4 f4 = *reinterpret_cast<const float4*>(feat + (size_t)pair * 256 + lane * 4);

        // per-half xyz sums over all 32 raw points (reference mean is unmasked)
        float sx = f4.x, sy = f4.y, sz = f4.z;
        #pragma unroll
        for (int off = 1; off < 32; off <<= 1) {
            sx += __shfl_xor(sx, off);
            sy += __shfl_xor(sy, off);
            sz += __shfl_xor(sz, off);
        }

        #pragma unroll
        for (int h = 0; h < 2; ++h) {
            const int p = p0 + h;
            int nv = nvox[p]; nv = nv < 1 ? 1 : (nv > NPTS ? NPTS : nv);
            const float cx = (float)coors[p * 4 + 3] * 0.2f + 0.1f;
            const float cy = (float)coors[p * 4 + 2] * 0.2f + (-39.9f);
            const float inv = 1.f / (float)nv;
            const float m0 = __shfl(sx, 32 * h) * inv;
            const float m1 = __shfl(sy, 32 * h) * inv;
            const float m2 = __shfl(sz, 32 * h) * inv;

            // fetch point (c31) of pillar h from the lane that loaded it
            const int s = 32 * h + c31;
            const float X = __shfl(f4.x, s), Y = __shfl(f4.y, s);
            const float Z = __shfl(f4.z, s), I = __shfl(f4.w, s);

            // A-frag: lanes<32 hold k=0..7, lanes>=32 hold k=8..15 (only k=8 used)
            const unsigned lo0 = pk2(X, Y),        lo1 = pk2(Z, I);
            const unsigned lo2 = pk2(X - m0, Y - m1), lo3 = pk2(Z - m2, X - cx);
            const unsigned hi0 = pk2(Y - cy, 0.f);
            const bool valid = (c31 < nv);          // zero rows n>=nv -> x'==0 there
            unsigned w0 = hiL ? hi0 : lo0;
            unsigned w1 = hiL ? 0u : lo1;
            unsigned w2 = hiL ? 0u : lo2;
            unsigned w3 = hiL ? 0u : lo3;
            union { unsigned u[4]; short8v v; } A_;
            A_.u[0] = valid ? w0 : 0u; A_.u[1] = valid ? w1 : 0u;
            A_.u[2] = valid ? w2 : 0u; A_.u[3] = valid ? w3 : 0u;

            f32x16 c0 = {0,0,0,0,0,0,0,0,0,0,0,0,0,0,0,0};
            f32x16 c1 = {0,0,0,0,0,0,0,0,0,0,0,0,0,0,0,0};
            c0 = __builtin_amdgcn_mfma_f32_32x32x16_bf16(A_.v, Bf[0], c0, 0, 0, 0);
            c1 = __builtin_amdgcn_mfma_f32_32x32x16_bf16(A_.v, Bf[1], c1, 0, 0, 0);

            // epilogue: per-col (lane&31) sums/max over this lane-half's 16 rows
            float s0 = 0.f, q0 = 0.f, x0m = -3.4e38f;
            float s1 = 0.f, q1 = 0.f, x1m = -3.4e38f;
            #pragma unroll
            for (int r = 0; r < 16; ++r) {
                const float x0 = c0[r], x1 = c1[r];
                s0 += x0; q0 = fmaf(x0, x0, q0); x0m = fmaxf(x0m, x0);
                s1 += x1; q1 = fmaf(x1, x1, q1); x1m = fmaxf(x1m, x1);
            }
            // combine the two lane-halves (rows 0-15 vs 4-19 etc: full 32 rows)
            s0 += __shfl_xor(s0, 32); q0 += __shfl_xor(q0, 32); x0m = fmaxf(x0m, __shfl_xor(x0m, 32));
            s1 += __shfl_xor(s1, 32); q1 += __shfl_xor(q1, 32); x1m = fmaxf(x1m, __shfl_xor(x1m, 32));
            // lane u holds col u&31 of both tiles; unit u lives in tile u>>5
            lsum += hiL ? s1 : s0;
            lsq  += hiL ? q1 : q0;
            xext[(size_t)p * UNITS + lane] = hiL ? x1m : x0m;
        }
    }

    ps[wave][lane]      = lsum;
    ps[wave][64 + lane] = lsq;
    __syncthreads();
    if (tid < 128)
        partials[blockIdx.x * 128 + tid] = ps[0][tid] + ps[1][tid] + ps[2][tid] + ps[3][tid];
}

__global__ __launch_bounds__(256)
void pfn_finalize(const float* __restrict__ partials,
                  const float* __restrict__ gamma,
                  const float* __restrict__ beta,
                  float*       __restrict__ ss)
{
    const int u = blockIdx.x;   // 0..63
    const int t = threadIdx.x;  // 0..255
    double aS = 0.0, aQ = 0.0;
    for (int b = t; b < SBLOCKS; b += 256) {
        aS += (double)partials[b * 128 + u];
        aQ += (double)partials[b * 128 + 64 + u];
    }
    __shared__ double sS[256], sQ[256];
    sS[t] = aS; sQ[t] = aQ;
    __syncthreads();
    for (int s = 128; s > 0; s >>= 1) {
        if (t < s) { sS[t] += sS[t + s]; sQ[t] += sQ[t + s]; }
        __syncthreads();
    }
    if (t == 0) {
        // sums are of x' = sg*x; mean'^2 == mean^2 and x'^2 == x^2, and
        // shift = beta - mean*scale = beta - mean'*|scale| (sg^2 = 1).
        const double inv_pn = 1.0 / ((double)PTOT * (double)NPTS);
        const double meanp = sS[0] * inv_pn;
        const double var   = sQ[0] * inv_pn - meanp * meanp;
        const float  absc  = fabsf(gamma[u]) * (float)(1.0 / sqrt(var + 1e-3));
        ss[u]      = absc;
        ss[64 + u] = beta[u] - (float)meanp * absc;
    }
}

// Apply: pure stream. Padded rows are exact zeros inside ext' already, so
// out = relu(|scale|*ext' + shift) with no nvox logic.
#define CBLOCKS 2500   // 2500*256 threads * 1 float4 = 2,560,000 floats exactly

__global__ __launch_bounds__(256)
void pfn_apply(const float*  __restrict__ ss,
               const float4* __restrict__ xext,
               float4*       __restrict__ out)
{
    const int i  = blockIdx.x * 256 + threadIdx.x;   // float4 index
    const int u0 = (i & 15) * 4;                     // first unit of this quad
    const float4 sc = *reinterpret_cast<const float4*>(ss + u0);
    const float4 sh = *reinterpret_cast<const float4*>(ss + 64 + u0);
    const float4 e  = xext[i];
    float4 o;
    o.x = fmaxf(fmaf(e.x, sc.x, sh.x), 0.f);
    o.y = fmaxf(fmaf(e.y, sc.y, sh.y), 0.f);
    o.z = fmaxf(fmaf(e.z, sc.z, sh.z), 0.f);
    o.w = fmaxf(fmaf(e.w, sc.w, sh.w), 0.f);
    out[i] = o;
}

extern "C" void kernel_launch(void* const* d_in, const int* in_sizes, int n_in,
                              void* d_out, int out_size, void* d_ws, size_t ws_size,
                              hipStream_t stream)
{
    const float* feat  = (const float*)d_in[0];
    const int*   nvox  = (const int*)d_in[1];
    const int*   coors = (const int*)d_in[2];
    const float* Wm    = (const float*)d_in[3];
    const float* gamma = (const float*)d_in[4];
    const float* beta  = (const float*)d_in[5];
    float* out = (float*)d_out;

    float* xext     = (float*)d_ws;                      // P*U floats = 10.24 MB
    float* partials = xext + (size_t)PTOT * UNITS;       // SBLOCKS*128 floats
    float* ss       = partials + (size_t)SBLOCKS * 128;  // 128 floats

    pfn_main<<<SBLOCKS, 256, 0, stream>>>(feat, nvox, coors, Wm, gamma, xext, partials);
    pfn_finalize<<<UNITS, 256, 0, stream>>>(partials, gamma, beta, ss);
    pfn_apply<<<CBLOCKS, 256, 0, stream>>>(ss, (const float4*)xext, (float4*)out);
}

// Round 10
// 38.922 us; speedup vs baseline: 2.1671x; 1.0204x over previous
//
#include <hip/hip_runtime.h>
#include <math.h>

#define NPTS    32
#define UNITS   64
#define PTOT    40000
#define NPAIRS  (PTOT / 2)          // 20000
#define SBLOCKS 2500
#define WPB     4                   // waves per block (256 threads)
#define TOTW    (SBLOCKS * WPB)     // 10000 waves
#define PPW     (NPAIRS / TOTW)     // 2 pairs per wave (exact)

// x[p,n,u] = b[p,u] + f0*wp0 + f1*wp1 + f2*wp2 + f3*wp3  (per lane = unit)
// wp folds W rows: wp0=W0+W4+W7, wp1=W1+W5+W8, wp2=W2+W6, wp3=W3
// b = -(m0*W4 + m1*W5 + m2*W6 + cx*W7 + cy*W8)
// sg = sign(gamma[u]) folded: chain yields x' = sg*x.
// BRANCHLESS: all 32 points processed, scalar-uniform predication, no breaks.
// xAv = (n<nv)?x':0 feeds sums AND max -> max includes the 0 candidates of
// padded rows exactly like the reference's mask-then-matmul, so apply needs
// no nvox logic at all.  Point broadcast via wave-uniform s_load_dwordx4
// batches (16 per chunk), fp32 FMA chain throughout.

__global__ __launch_bounds__(256, 8)
void pfn_main(const float* __restrict__ feat,
              const int*   __restrict__ nvox,
              const int*   __restrict__ coors,
              const float* __restrict__ Wm,
              const float* __restrict__ gamma,
              float*       __restrict__ xext,
              float*       __restrict__ partials)
{
    __shared__ float ps[WPB][128];

    const int tid  = threadIdx.x;
    const int lane = tid & 63;
    const int wave = __builtin_amdgcn_readfirstlane(tid >> 6);
    const int gwave = blockIdx.x * WPB + wave;

    const float sg  = (gamma[lane] >= 0.f) ? 1.f : -1.f;
    const float w4 = sg * Wm[4 * UNITS + lane], w5 = sg * Wm[5 * UNITS + lane];
    const float w6 = sg * Wm[6 * UNITS + lane], w7 = sg * Wm[7 * UNITS + lane];
    const float w8 = sg * Wm[8 * UNITS + lane];
    const float wp0 = sg * Wm[0 * UNITS + lane] + w4 + w7;
    const float wp1 = sg * Wm[1 * UNITS + lane] + w5 + w8;
    const float wp2 = sg * Wm[2 * UNITS + lane] + w6;
    const float wp3 = sg * Wm[3 * UNITS + lane];

    // ---- prefetch: vector loads + uniform meta for both pairs ----
    float4 fv[PPW];
    int nvAv[PPW], nvBv[PPW];
    float cxAv[PPW], cyAv[PPW], cxBv[PPW], cyBv[PPW];
    #pragma unroll
    for (int it = 0; it < PPW; ++it) {
        const int pair = it * TOTW + gwave;     // uniform
        const int p0 = pair * 2;                // uniform
        fv[it] = *reinterpret_cast<const float4*>(feat + (size_t)pair * 256 + lane * 4);
        int nvA = nvox[p0], nvB = nvox[p0 + 1];
        nvAv[it] = nvA < 1 ? 1 : (nvA > NPTS ? NPTS : nvA);
        nvBv[it] = nvB < 1 ? 1 : (nvB > NPTS ? NPTS : nvB);
        cxAv[it] = (float)coors[p0 * 4 + 3] * 0.2f + 0.1f;
        cyAv[it] = (float)coors[p0 * 4 + 2] * 0.2f + (-39.9f);
        cxBv[it] = (float)coors[p0 * 4 + 7] * 0.2f + 0.1f;
        cyBv[it] = (float)coors[p0 * 4 + 6] * 0.2f + (-39.9f);
    }

    float lsum = 0.f, lsq = 0.f;   // sums of x' = sg*x (masked rows contribute 0)

    #pragma unroll
    for (int it = 0; it < PPW; ++it) {
        const int pair = it * TOTW + gwave;
        const int p0 = pair * 2;

        // per-half xyz sums over all 32 raw points (reference mean is unmasked)
        float sx = fv[it].x, sy = fv[it].y, sz = fv[it].z;
        #pragma unroll
        for (int off = 1; off < 32; off <<= 1) {
            sx += __shfl_xor(sx, off);
            sy += __shfl_xor(sy, off);
            sz += __shfl_xor(sz, off);
        }

        const int nvA = nvAv[it], nvB = nvBv[it];
        const float iA = 1.f / (float)nvA, iB = 1.f / (float)nvB;
        const float mA0 = __shfl(sx, 0)  * iA, mA1 = __shfl(sy, 0)  * iA, mA2 = __shfl(sz, 0)  * iA;
        const float mB0 = __shfl(sx, 32) * iB, mB1 = __shfl(sy, 32) * iB, mB2 = __shfl(sz, 32) * iB;
        const float bA = -(mA0 * w4 + mA1 * w5 + mA2 * w6 + cxAv[it] * w7 + cyAv[it] * w8);
        const float bB = -(mB0 * w4 + mB1 * w5 + mB2 * w6 + cxBv[it] * w7 + cyBv[it] * w8);

        // wave-uniform point bases -> s_load batches
        const float* fpA = feat + (size_t)p0 * 128;
        const float* fpB = fpA + 128;

        float mA = -3.4e38f, mB = -3.4e38f;

        #pragma unroll
        for (int c = 0; c < 4; ++c) {
            float4 a8[8], b8[8];                 // uniform -> scalar regs
            #pragma unroll
            for (int k = 0; k < 8; ++k) {
                a8[k] = *reinterpret_cast<const float4*>(fpA + (c * 8 + k) * 4);
                b8[k] = *reinterpret_cast<const float4*>(fpB + (c * 8 + k) * 4);
            }
            #pragma unroll
            for (int k = 0; k < 8; ++k) {
                const int n = c * 8 + k;         // compile-time within chunk
                const float xA = fmaf(a8[k].x, wp0, fmaf(a8[k].y, wp1, fmaf(a8[k].z, wp2, fmaf(a8[k].w, wp3, bA))));
                const float xB = fmaf(b8[k].x, wp0, fmaf(b8[k].y, wp1, fmaf(b8[k].z, wp2, fmaf(b8[k].w, wp3, bB))));
                const float xAv = (n < nvA) ? xA : 0.f;   // uniform predicate
                const float xBv = (n < nvB) ? xB : 0.f;
                lsum += xAv;  lsq = fmaf(xAv, xA, lsq);   // xAv*xA == xA^2 or 0
                lsum += xBv;  lsq = fmaf(xBv, xB, lsq);
                mA = fmaxf(mA, xAv);   // masked-to-0 candidate == reference's zero rows
                mB = fmaxf(mB, xBv);
            }
        }

        xext[(size_t)p0 * UNITS + lane]       = mA;   // max(x'), sg NOT re-applied
        xext[(size_t)(p0 + 1) * UNITS + lane] = mB;
    }

    ps[wave][lane]      = lsum;    // sums of x'
    ps[wave][64 + lane] = lsq;     // x'^2 == x^2
    __syncthreads();
    if (tid < 128)
        partials[blockIdx.x * 128 + tid] = ps[0][tid] + ps[1][tid] + ps[2][tid] + ps[3][tid];
}

__global__ __launch_bounds__(256)
void pfn_finalize(const float* __restrict__ partials,
                  const float* __restrict__ gamma,
                  const float* __restrict__ beta,
                  float*       __restrict__ ss)
{
    const int u = blockIdx.x;   // 0..63
    const int t = threadIdx.x;  // 0..255
    double aS = 0.0, aQ = 0.0;
    for (int b = t; b < SBLOCKS; b += 256) {
        aS += (double)partials[b * 128 + u];
        aQ += (double)partials[b * 128 + 64 + u];
    }
    __shared__ double sS[256], sQ[256];
    sS[t] = aS; sQ[t] = aQ;
    __syncthreads();
    for (int s = 128; s > 0; s >>= 1) {
        if (t < s) { sS[t] += sS[t + s]; sQ[t] += sQ[t + s]; }
        __syncthreads();
    }
    if (t == 0) {
        // sums are of x' = sg*x: mean'^2 == mean^2, x'^2 == x^2.
        // scale*x_ext = |scale|*max(x'); shift = beta - mean'*|scale|.
        const double inv_pn = 1.0 / ((double)PTOT * (double)NPTS);
        const double meanp = sS[0] * inv_pn;
        const double var   = sQ[0] * inv_pn - meanp * meanp;
        const float  absc  = fabsf(gamma[u]) * (float)(1.0 / sqrt(var + 1e-3));
        ss[u]      = absc;
        ss[64 + u] = beta[u] - (float)meanp * absc;
    }
}

// Apply: pure 2-stream. Padded-row candidates are already inside ext.
#define CBLOCKS 2500   // 2500*256 threads * 1 float4 = 2,560,000 floats exactly

__global__ __launch_bounds__(256)
void pfn_apply(const float*  __restrict__ ss,
               const float4* __restrict__ xext,
               float4*       __restrict__ out)
{
    const int i  = blockIdx.x * 256 + threadIdx.x;   // float4 index
    const int u0 = (i & 15) * 4;                     // first unit of this quad
    const float4 sc = *reinterpret_cast<const float4*>(ss + u0);
    const float4 sh = *reinterpret_cast<const float4*>(ss + 64 + u0);
    const float4 e  = xext[i];
    float4 o;
    o.x = fmaxf(fmaf(e.x, sc.x, sh.x), 0.f);
    o.y = fmaxf(fmaf(e.y, sc.y, sh.y), 0.f);
    o.z = fmaxf(fmaf(e.z, sc.z, sh.z), 0.f);
    o.w = fmaxf(fmaf(e.w, sc.w, sh.w), 0.f);
    out[i] = o;
}

extern "C" void kernel_launch(void* const* d_in, const int* in_sizes, int n_in,
                              void* d_out, int out_size, void* d_ws, size_t ws_size,
                              hipStream_t stream)
{
    const float* feat  = (const float*)d_in[0];
    const int*   nvox  = (const int*)d_in[1];
    const int*   coors = (const int*)d_in[2];
    const float* Wm    = (const float*)d_in[3];
    const float* gamma = (const float*)d_in[4];
    const float* beta  = (const float*)d_in[5];
    float* out = (float*)d_out;

    float* xext     = (float*)d_ws;                      // P*U floats = 10.24 MB
    float* partials = xext + (size_t)PTOT * UNITS;       // SBLOCKS*128 floats
    float* ss       = partials + (size_t)SBLOCKS * 128;  // 128 floats

    pfn_main<<<SBLOCKS, 256, 0, stream>>>(feat, nvox, coors, Wm, gamma, xext, partials);
    pfn_finalize<<<UNITS, 256, 0, stream>>>(partials, gamma, beta, ss);
    pfn_apply<<<CBLOCKS, 256, 0, stream>>>(ss, (const float4*)xext, (float4*)out);
}

// Round 11
// 31.241 us; speedup vs baseline: 2.6999x; 1.2459x over previous
//
#include <hip/hip_runtime.h>
#include <math.h>

#define NPTS    32
#define UNITS   64
#define PTOT    40000
#define NPAIRS  (PTOT / 2)          // 20000
#define SBLOCKS 2500
#define WPB     4                   // waves per block (256 threads)
#define TOTW    (SBLOCKS * WPB)     // 10000 waves
#define PPW     (NPAIRS / TOTW)     // 2 pairs per wave (exact)
#define NSLOTS  16                  // partial-merge slots (atomicAdd fan-in 156/addr)

// x[p,n,u] = b[p,u] + f0*wp0 + f1*wp1 + f2*wp2 + f3*wp3  (per lane = unit)
// wp folds W rows: wp0=W0+W4+W7, wp1=W1+W5+W8, wp2=W2+W6, wp3=W3
// b = -(m0*W4 + m1*W5 + m2*W6 + cx*W7 + cy*W8)
// sg = sign(gamma[u]) folded: chain yields x' = sg*x; we track max(x') over
// valid points, then fold the padded-row candidate (0) in when nv<32 -- this
// reproduces the reference's mask-then-matmul max exactly, so apply is a pure
// stream: out = relu(|scale|*ext + shift), shift = beta - mean'*|scale|.
// Point broadcast via wave-uniform s_load (R4 structure, best measured).
// Stats: per-block LDS reduce -> 16-slot atomicAdd merge (no finalize kernel).

__global__ __launch_bounds__(256)
void pfn_main(const float* __restrict__ feat,
              const int*   __restrict__ nvox,
              const int*   __restrict__ coors,
              const float* __restrict__ Wm,
              const float* __restrict__ gamma,
              float*       __restrict__ xext,
              float*       __restrict__ slots)
{
    __shared__ float ps[WPB][128];

    const int tid  = threadIdx.x;
    const int lane = tid & 63;
    const int wave = __builtin_amdgcn_readfirstlane(tid >> 6);
    const int gwave = blockIdx.x * WPB + wave;

    const float sg  = (gamma[lane] >= 0.f) ? 1.f : -1.f;
    const float w4 = sg * Wm[4 * UNITS + lane], w5 = sg * Wm[5 * UNITS + lane];
    const float w6 = sg * Wm[6 * UNITS + lane], w7 = sg * Wm[7 * UNITS + lane];
    const float w8 = sg * Wm[8 * UNITS + lane];
    const float wp0 = sg * Wm[0 * UNITS + lane] + w4 + w7;
    const float wp1 = sg * Wm[1 * UNITS + lane] + w5 + w8;
    const float wp2 = sg * Wm[2 * UNITS + lane] + w6;
    const float wp3 = sg * Wm[3 * UNITS + lane];

    float lsum = 0.f, lsq = 0.f;   // sums of x' = sg*x over valid points

    #pragma unroll
    for (int it = 0; it < PPW; ++it) {
        const int pair = it * TOTW + gwave;   // uniform
        const int p0 = pair * 2;              // uniform

        // coalesced vector load (1 KB/wave) for the points-mean butterfly
        const float4 f4 = *reinterpret_cast<const float4*>(feat + (size_t)pair * 256 + lane * 4);
        float sx = f4.x, sy = f4.y, sz = f4.z;
        #pragma unroll
        for (int off = 1; off < 32; off <<= 1) {
            sx += __shfl_xor(sx, off);
            sy += __shfl_xor(sy, off);
            sz += __shfl_xor(sz, off);
        }

        int nvA = nvox[p0], nvB = nvox[p0 + 1];       // uniform -> s_load
        nvA = nvA < 1 ? 1 : (nvA > NPTS ? NPTS : nvA);
        nvB = nvB < 1 ? 1 : (nvB > NPTS ? NPTS : nvB);
        const float cxA = (float)coors[p0 * 4 + 3] * 0.2f + 0.1f;
        const float cyA = (float)coors[p0 * 4 + 2] * 0.2f + (-39.9f);
        const float cxB = (float)coors[p0 * 4 + 7] * 0.2f + 0.1f;
        const float cyB = (float)coors[p0 * 4 + 6] * 0.2f + (-39.9f);
        const float iA  = 1.f / (float)nvA,  iB  = 1.f / (float)nvB;
        const float mA0 = __shfl(sx, 0)  * iA, mA1 = __shfl(sy, 0)  * iA, mA2 = __shfl(sz, 0)  * iA;
        const float mB0 = __shfl(sx, 32) * iB, mB1 = __shfl(sy, 32) * iB, mB2 = __shfl(sz, 32) * iB;
        const float bA = -(mA0 * w4 + mA1 * w5 + mA2 * w6 + cxA * w7 + cyA * w8);
        const float bB = -(mB0 * w4 + mB1 * w5 + mB2 * w6 + cxB * w7 + cyB * w8);

        // uniform point bases: whole wave reads the same point -> s_load
        const float* fpA = feat + (size_t)p0 * 128;
        const float* fpB = fpA + 128;

        float mA = -3.4e38f, mB = -3.4e38f;
        const int nmin = nvA < nvB ? nvA : nvB;

        #pragma unroll 4
        for (int n = 0; n < nmin; ++n) {
            const float4 a  = *reinterpret_cast<const float4*>(fpA + n * 4);
            const float4 b4 = *reinterpret_cast<const float4*>(fpB + n * 4);
            const float xA = fmaf(a.x,  wp0, fmaf(a.y,  wp1, fmaf(a.z,  wp2, fmaf(a.w,  wp3, bA))));
            const float xB = fmaf(b4.x, wp0, fmaf(b4.y, wp1, fmaf(b4.z, wp2, fmaf(b4.w, wp3, bB))));
            lsum += xA; lsq = fmaf(xA, xA, lsq); mA = fmaxf(mA, xA);
            lsum += xB; lsq = fmaf(xB, xB, lsq); mB = fmaxf(mB, xB);
        }
        #pragma unroll 4
        for (int n = nmin; n < nvA; ++n) {            // at most one tail loop runs
            const float4 a = *reinterpret_cast<const float4*>(fpA + n * 4);
            const float xA = fmaf(a.x, wp0, fmaf(a.y, wp1, fmaf(a.z, wp2, fmaf(a.w, wp3, bA))));
            lsum += xA; lsq = fmaf(xA, xA, lsq); mA = fmaxf(mA, xA);
        }
        #pragma unroll 4
        for (int n = nmin; n < nvB; ++n) {
            const float4 b4 = *reinterpret_cast<const float4*>(fpB + n * 4);
            const float xB = fmaf(b4.x, wp0, fmaf(b4.y, wp1, fmaf(b4.z, wp2, fmaf(b4.w, wp3, bB))));
            lsum += xB; lsq = fmaf(xB, xB, lsq); mB = fmaxf(mB, xB);
        }

        // fold the padded-row candidate (x'==0) into the max when nv<32
        if (nvA < NPTS) mA = fmaxf(mA, 0.f);          // uniform predicate
        if (nvB < NPTS) mB = fmaxf(mB, 0.f);

        xext[(size_t)p0 * UNITS + lane]       = mA;   // max(x'), sg NOT re-applied
        xext[(size_t)(p0 + 1) * UNITS + lane] = mB;
    }

    ps[wave][lane]      = lsum;    // sums of x' ; x'^2 == x^2
    ps[wave][64 + lane] = lsq;
    __syncthreads();
    if (tid < 128) {
        const float v = ps[0][tid] + ps[1][tid] + ps[2][tid] + ps[3][tid];
        atomicAdd(&slots[(blockIdx.x & (NSLOTS - 1)) * 128 + tid], v);  // ~156 RMW/addr
    }
}

// Apply: per-block BN finalize from the 16x128 slot array (8 KB, L2-hot),
// then pure 2-stream: out = relu(|scale|*ext + shift). No nvox logic.
#define CBLOCKS 2500   // 2500*256 threads * 1 float4 = 2,560,000 floats exactly

__global__ __launch_bounds__(256)
void pfn_apply(const float*  __restrict__ slots,
               const float*  __restrict__ gamma,
               const float*  __restrict__ beta,
               const float4* __restrict__ xext,
               float4*       __restrict__ out)
{
    __shared__ __align__(16) float s_sc[64], s_sh[64];
    const int t = threadIdx.x;
    if (t < 64) {
        float S = 0.f, Q = 0.f;
        #pragma unroll
        for (int s = 0; s < NSLOTS; ++s) {
            S += slots[s * 128 + t];
            Q += slots[s * 128 + 64 + t];
        }
        // sums are of x' = sg*x: mean'^2 == mean^2, x'^2 == x^2.
        // scale*ext_x = |scale|*max(x'); shift = beta - mean'*|scale|.
        const float INV_PN = 1.0f / (float)(PTOT * NPTS);
        const float mean = S * INV_PN;
        const float var  = Q * INV_PN - mean * mean;
        const float absc = fabsf(gamma[t]) * rsqrtf(var + 1e-3f);
        s_sc[t] = absc;
        s_sh[t] = beta[t] - mean * absc;
    }
    __syncthreads();

    const int i  = blockIdx.x * 256 + t;             // float4 index
    const int u0 = (i & 15) * 4;                     // first unit of this quad
    const float4 sc = *reinterpret_cast<const float4*>(&s_sc[u0]);
    const float4 sh = *reinterpret_cast<const float4*>(&s_sh[u0]);
    const float4 e  = xext[i];
    float4 o;
    o.x = fmaxf(fmaf(e.x, sc.x, sh.x), 0.f);
    o.y = fmaxf(fmaf(e.y, sc.y, sh.y), 0.f);
    o.z = fmaxf(fmaf(e.z, sc.z, sh.z), 0.f);
    o.w = fmaxf(fmaf(e.w, sc.w, sh.w), 0.f);
    out[i] = o;
}

extern "C" void kernel_launch(void* const* d_in, const int* in_sizes, int n_in,
                              void* d_out, int out_size, void* d_ws, size_t ws_size,
                              hipStream_t stream)
{
    const float* feat  = (const float*)d_in[0];
    const int*   nvox  = (const int*)d_in[1];
    const int*   coors = (const int*)d_in[2];
    const float* Wm    = (const float*)d_in[3];
    const float* gamma = (const float*)d_in[4];
    const float* beta  = (const float*)d_in[5];
    float* out = (float*)d_out;

    float* xext  = (float*)d_ws;                       // P*U floats = 10.24 MB
    float* slots = xext + (size_t)PTOT * UNITS;        // NSLOTS*128 floats = 8 KB

    hipMemsetAsync(slots, 0, NSLOTS * 128 * sizeof(float), stream);  // ws not re-zeroed by harness
    pfn_main<<<SBLOCKS, 256, 0, stream>>>(feat, nvox, coors, Wm, gamma, xext, slots);
    pfn_apply<<<CBLOCKS, 256, 0, stream>>>(slots, gamma, beta, (const float4*)xext, (float4*)out);
}